// Round 5
// baseline (204.211 us; speedup 1.0000x reference)
//
#include <hip/hip_runtime.h>
#include <math.h>

#define Bb 8
#define Hh 8
#define LQ 2048
#define LK 2048
#define Dd 64
#define Uu 40
#define NCH 32
#define CHUNK (LK / NCH)   // 64
#define NSPL 8
#define CK (LK / NSPL)     // 256 keys per split-K chunk
#define UW 10              // queries per wave in k_attn_part

__device__ __forceinline__ float dot4(float4 a, float4 b) {
    return a.x * b.x + a.y * b.y + a.z * b.z + a.w * b.w;
}

// ---------------- Stage 1: M[b,h,q] = max_s(QK_s) - mean_s(QK_s) ----------------
// wave = 1 query; lane owns 8 floats of head lane>>3; coalesced 2KB gather serves 8 heads.
// Software-pipelined 2 samples/iter (4 loads in flight) for L2-latency hiding.
__global__ __launch_bounds__(256, 8) void k_sampleM(
    const float* __restrict__ Qp, const float* __restrict__ Kp,
    const int* __restrict__ idxs, float* __restrict__ M)
{
    int b  = blockIdx.x & 7;      // b-major: round-robin XCD dispatch pins K[b] (4MB) per XCD L2
    int qt = blockIdx.x >> 3;     // 0..511 (4 queries per block)
    int t = threadIdx.x;
    int lane = t & 63, wave = t >> 6;

    __shared__ int sIdx[4 * Uu];
    if (t < 4 * Uu) sIdx[t] = idxs[qt * (4 * Uu) + t];
    __syncthreads();

    const size_t HD = (size_t)Hh * Dd;   // 512
    int q = qt * 4 + wave;
    const float4* Qv = reinterpret_cast<const float4*>(
        Qp + ((size_t)b * LQ + q) * HD + lane * 8);
    float4 qa = Qv[0], qb = Qv[1];

    const float* Kb = Kp + (size_t)b * LK * HD + lane * 8;
    const int* myIdx = &sIdx[wave * Uu];

    // preload samples 0,1
    const float4* K0 = reinterpret_cast<const float4*>(Kb + (size_t)myIdx[0] * HD);
    const float4* K1 = reinterpret_cast<const float4*>(Kb + (size_t)myIdx[1] * HD);
    float4 ka0 = K0[0], kb0 = K0[1];
    float4 ka1 = K1[0], kb1 = K1[1];

    float mx = -INFINITY, sm = 0.f;
#pragma unroll 4
    for (int s = 0; s < Uu; s += 2) {
        float4 na0, nb0, na1, nb1;
        if (s + 2 < Uu) {
            const float4* N0 = reinterpret_cast<const float4*>(Kb + (size_t)myIdx[s + 2] * HD);
            const float4* N1 = reinterpret_cast<const float4*>(Kb + (size_t)myIdx[s + 3] * HD);
            na0 = N0[0]; nb0 = N0[1];
            na1 = N1[0]; nb1 = N1[1];
        }
        float p0 = dot4(qa, ka0) + dot4(qb, kb0);
        p0 += __shfl_xor(p0, 1, 64);
        p0 += __shfl_xor(p0, 2, 64);
        p0 += __shfl_xor(p0, 4, 64);
        mx = fmaxf(mx, p0); sm += p0;

        float p1 = dot4(qa, ka1) + dot4(qb, kb1);
        p1 += __shfl_xor(p1, 1, 64);
        p1 += __shfl_xor(p1, 2, 64);
        p1 += __shfl_xor(p1, 4, 64);
        mx = fmaxf(mx, p1); sm += p1;

        ka0 = na0; kb0 = nb0; ka1 = na1; kb1 = nb1;
    }
    if ((lane & 7) == 0) {
        int h = lane >> 3;
        M[((b * 8 + h) << 11) + q] = mx - sm * (1.0f / Uu);
    }
}

// ---------------- Stage 2: top-40 per (b,h) — single wave, shuffle argmax, 0 barriers ----
__global__ __launch_bounds__(64) void k_topk(
    const float* __restrict__ M, int* __restrict__ Mtop, int* __restrict__ sel)
{
    int bh = blockIdx.x;
    int lane = threadIdx.x;
    __shared__ float Ml[LQ];

    for (int j = lane; j < LQ; j += 64) {
        Ml[j] = M[bh * LQ + j];
        sel[bh * LQ + j] = -1;
    }
    __syncthreads();

    float lv = -INFINITY; int li = LQ;
    for (int j = 0; j < 32; ++j) {
        int idx = lane + 64 * j;
        float x = Ml[idx];
        if (x > lv) { lv = x; li = idx; }
    }

    for (int u = 0; u < Uu; ++u) {
        float v = lv; int id = li;
#pragma unroll
        for (int off = 32; off > 0; off >>= 1) {
            float ov = __shfl_xor(v, off, 64);
            int   oi = __shfl_xor(id, off, 64);
            if (ov > v || (ov == v && oi < id)) { v = ov; id = oi; }
        }
        if (lane == 0) {
            Mtop[bh * Uu + u] = id;
            sel[bh * LQ + id] = u;
        }
        if ((id & 63) == lane) {        // owner invalidates + rescans its column
            Ml[id] = -INFINITY;
            lv = -INFINITY; li = LQ;
            for (int j = 0; j < 32; ++j) {
                int idx = lane + 64 * j;
                float x = Ml[idx];
                if (x > lv) { lv = x; li = idx; }
            }
        }
    }
}

// ---------------- Stage 3a: split-K partial attention (no max-sub softmax) ----------------
__global__ __launch_bounds__(256) void k_attn_part(
    const float* __restrict__ Qp, const float* __restrict__ Kp,
    const float* __restrict__ Vp, const int* __restrict__ Mtop,
    float* __restrict__ pacc, float* __restrict__ pl)
{
    int bh = blockIdx.x >> 3;
    int c  = blockIdx.x & (NSPL - 1);
    int b = bh >> 3, h = bh & 7;
    int lane = threadIdx.x & 63, wave = threadIdx.x >> 6;

    __shared__ float sQ[Uu][Dd];
    __shared__ int   sP[Uu];
    __shared__ float sE[4][UW][Dd];

    if (threadIdx.x < Uu) sP[threadIdx.x] = Mtop[bh * Uu + threadIdx.x];
    __syncthreads();
    for (int i = threadIdx.x; i < Uu * Dd; i += 256) {
        int u = i >> 6, d = i & 63;
        sQ[u][d] = Qp[(((size_t)b * LQ + sP[u]) * Hh + h) * Dd + d];
    }
    __syncthreads();

    float acc[UW], lsum[UW];
#pragma unroll
    for (int i = 0; i < UW; ++i) { acc[i] = 0.f; lsum[i] = 0.f; }

    const int u0 = wave * UW;
    for (int t = 0; t < CK / 64; ++t) {
        int k0 = c * CK + t * 64;
        int k  = k0 + lane;

        int need = 0;
#pragma unroll
        for (int uu = 0; uu < UW; ++uu) need |= (sP[u0 + uu] >= k0) ? 1 : 0;
        if (!need) continue;   // wave-uniform skip

        const float4* Kv = reinterpret_cast<const float4*>(
            Kp + (((size_t)b * LK + k) * Hh + h) * Dd);
        float4 kr[16];
#pragma unroll
        for (int j = 0; j < 16; ++j) kr[j] = Kv[j];

#pragma unroll
        for (int uu = 0; uu < UW; ++uu) {
            int p = sP[u0 + uu];
            if (p < k0) continue;
            const float4* Q4 = reinterpret_cast<const float4*>(sQ[u0 + uu]);
            float s = 0.f;
#pragma unroll
            for (int j = 0; j < 16; ++j) s += dot4(kr[j], Q4[j]);
            float e = (k <= p) ? __expf(s * 0.125f) : 0.f;
            sE[wave][uu][lane] = e;
        }

        const float* Vb = Vp + (((size_t)b * LK + k0) * Hh + h) * Dd + lane;
        float vc[64];
#pragma unroll
        for (int kk = 0; kk < 64; ++kk) vc[kk] = Vb[(size_t)kk * (Hh * Dd)];

#pragma unroll
        for (int uu = 0; uu < UW; ++uu) {
            int p = sP[u0 + uu];
            if (p < k0) continue;
            const float4* E4 = reinterpret_cast<const float4*>(sE[wave][uu]);
            float a = acc[uu], L = lsum[uu];
#pragma unroll
            for (int j = 0; j < 16; ++j) {
                float4 e4 = E4[j];
                a += e4.x * vc[4 * j + 0] + e4.y * vc[4 * j + 1]
                   + e4.z * vc[4 * j + 2] + e4.w * vc[4 * j + 3];
                L += (e4.x + e4.y) + (e4.z + e4.w);
            }
            acc[uu] = a; lsum[uu] = L;
        }
    }

#pragma unroll
    for (int uu = 0; uu < UW; ++uu) {
        int u = u0 + uu;
        pacc[(((size_t)bh * NSPL + c) * Uu + u) * Dd + lane] = acc[uu];
        if (lane == 0) pl[((size_t)bh * NSPL + c) * Uu + u] = lsum[uu];
    }
}

// ---------------- Stage 3b: combine split-K partials ----------------
__global__ __launch_bounds__(256) void k_attn_comb(
    const float* __restrict__ pacc, const float* __restrict__ pl,
    float* __restrict__ attn)
{
    int gid = blockIdx.x * 4 + (threadIdx.x >> 6);
    int lane = threadIdx.x & 63;
    int bh = gid / Uu, u = gid % Uu;

    float A = 0.f, L = 0.f;
#pragma unroll
    for (int c = 0; c < NSPL; ++c) {
        A += pacc[(((size_t)bh * NSPL + c) * Uu + u) * Dd + lane];
        L += pl[((size_t)bh * NSPL + c) * Uu + u];
    }
    attn[(bh * Uu + u) * Dd + lane] = A / L;
}

// ---------------- Stage 4a: per-chunk partial sums of V (float4, 16dq x 4r) -------------
__global__ __launch_bounds__(64) void k_part(
    const float* __restrict__ Vp, float* __restrict__ part)
{
    int c  = blockIdx.x & (NCH - 1);
    int bh = blockIdx.x >> 5;
    int b = bh >> 3, h = bh & 7;
    int dq = threadIdx.x & 15, r = threadIdx.x >> 4;

    const float* vb = Vp + (((size_t)b * LK + c * CHUNK) * Hh + h) * Dd + dq * 4;
    float sx = 0.f, sy = 0.f, sz = 0.f, sw = 0.f;
    for (int l = r; l < CHUNK; l += 4) {
        float4 v = *reinterpret_cast<const float4*>(vb + (size_t)l * (Hh * Dd));
        sx += v.x; sy += v.y; sz += v.z; sw += v.w;
    }
    sx += __shfl_xor(sx, 16, 64); sy += __shfl_xor(sy, 16, 64);
    sz += __shfl_xor(sz, 16, 64); sw += __shfl_xor(sw, 16, 64);
    sx += __shfl_xor(sx, 32, 64); sy += __shfl_xor(sy, 32, 64);
    sz += __shfl_xor(sz, 32, 64); sw += __shfl_xor(sw, 32, 64);
    if (r == 0) {
        float4 s4 = make_float4(sx, sy, sz, sw);
        *reinterpret_cast<float4*>(&part[(size_t)(bh * NCH + c) * Dd + dq * 4]) = s4;
    }
}

// ---------------- Stage 4b: exclusive prefix over chunks ----------------
__global__ __launch_bounds__(64) void k_prefix(
    const float* __restrict__ part, float* __restrict__ pfx)
{
    int bh = blockIdx.x;
    int d = threadIdx.x;
    float run = 0.f;
    for (int c = 0; c < NCH; ++c) {
        pfx[(size_t)(bh * NCH + c) * Dd + d] = run;
        run += part[(size_t)(bh * NCH + c) * Dd + d];
    }
}

// ---------------- Stage 4c: cumsum + scatter attn rows -> output ----------------
__global__ __launch_bounds__(64) void k_scan(
    const float* __restrict__ Vp, const float* __restrict__ pfx,
    const int* __restrict__ sel, const float* __restrict__ attn,
    float* __restrict__ out)
{
    int c  = blockIdx.x & (NCH - 1);
    int bh = blockIdx.x >> 5;
    int b = bh >> 3, h = bh & 7;
    int d = threadIdx.x;

    float run = pfx[(size_t)(bh * NCH + c) * Dd + d];
    int l0 = c * CHUNK;
    const float* vb = Vp + (((size_t)b * LK + l0) * Hh + h) * Dd + d;
    float* ob = out + (((size_t)b * LQ + l0) * Hh + h) * Dd + d;
    const int* sb = sel + bh * LQ + l0;

#pragma unroll 4
    for (int l = 0; l < CHUNK; ++l) {
        float v = vb[(size_t)l * (Hh * Dd)];
        int s = sb[l];
        int si = (s >= 0) ? s : 0;
        float av = attn[(bh * Uu + si) * Dd + d];
        run += v;
        ob[(size_t)l * (Hh * Dd)] = (s >= 0) ? av : run;
    }
}

extern "C" void kernel_launch(void* const* d_in, const int* in_sizes, int n_in,
                              void* d_out, int out_size, void* d_ws, size_t ws_size,
                              hipStream_t stream) {
    const float* Qp   = (const float*)d_in[0];
    const float* Kp   = (const float*)d_in[1];
    const float* Vp   = (const float*)d_in[2];
    const int*   idxs = (const int*)d_in[3];
    float* out = (float*)d_out;

    char* w = (char*)d_ws;
    float* M    = (float*)(w);                 // 512K (dead after k_topk -> reused as pfx)
    int*   sel  = (int*)  (w + 512 * 1024);    // 512K
    float* attn = (float*)(w + 1024 * 1024);   // 640K
    int*   Mtop = (int*)  (w + 1664 * 1024);   // 16K
    float* part = (float*)(w + 1680 * 1024);   // 512K
    float* pacc = (float*)(w + 2304 * 1024);   // 5120K (64*8*40*64 f)
    float* pl   = (float*)(w + 7424 * 1024);   // 80K
    float* pfx  = M;                           // reuse (M dead after k_topk)

    k_sampleM<<<Bb * (LQ / 4), 256, 0, stream>>>(Qp, Kp, idxs, M);
    k_topk<<<Bb * Hh, 64, 0, stream>>>(M, Mtop, sel);
    k_attn_part<<<Bb * Hh * NSPL, 256, 0, stream>>>(Qp, Kp, Vp, Mtop, pacc, pl);
    k_attn_comb<<<(Bb * Hh * Uu) / 4, 256, 0, stream>>>(pacc, pl, attn);
    k_part<<<Bb * Hh * NCH, 64, 0, stream>>>(Vp, part);
    k_prefix<<<Bb * Hh, 64, 0, stream>>>(part, pfx);
    k_scan<<<Bb * Hh * NCH, 64, 0, stream>>>(Vp, pfx, sel, attn, out);
}